// Round 3
// baseline (482.561 us; speedup 1.0000x reference)
//
#include <hip/hip_runtime.h>
#include <math.h>

#define IN_FEATS 64
#define N_NODES 100000
#define N_EDGES 1600000
#define NSCAN_BLOCKS ((N_NODES + 1023) / 1024)   // 98

// ---------------------------------------------------------------------------
// edge coefficient: rbf(d, mu_k) * smooth_cutoff(d)
// ---------------------------------------------------------------------------
__device__ __forceinline__ float edge_coef(float d, float mu) {
    float t = d - mu;
    float rbf = __expf(-64.0f * t * t);          // gamma = 64/(1-0)
    float x  = (d - 0.8f) * 5.0f;                // /(1.0-0.8)
    float xc = fminf(fmaxf(x, 0.0f), 1.0f);
    float ramp = 0.5f * (__cosf(3.14159265358979323846f * xc) + 1.0f);
    float fc = (d <= 0.8f) ? 1.0f : ((d >= 1.0f) ? 0.0f : ramp);
    return rbf * fc;
}

// ---------------------------------------------------------------------------
// CSR build: count -> scan -> scatter
// ---------------------------------------------------------------------------
__global__ __launch_bounds__(256) void count_kernel(const int* __restrict__ dst,
                                                    int* __restrict__ cnt) {
    int e = blockIdx.x * 256 + threadIdx.x;
    if (e < N_EDGES) atomicAdd(&cnt[dst[e]], 1);
}

__global__ __launch_bounds__(256) void scan1_kernel(const int* __restrict__ cnt,
                                                    int* __restrict__ offs,
                                                    int* __restrict__ bsums) {
    __shared__ int lds[256];
    int tid = threadIdx.x;
    int base = blockIdx.x * 1024 + tid * 4;
    int v0 = 0, v1 = 0, v2 = 0, v3 = 0;
    if (base + 3 < N_NODES) {
        v0 = cnt[base]; v1 = cnt[base + 1]; v2 = cnt[base + 2]; v3 = cnt[base + 3];
    } else {
        if (base     < N_NODES) v0 = cnt[base];
        if (base + 1 < N_NODES) v1 = cnt[base + 1];
        if (base + 2 < N_NODES) v2 = cnt[base + 2];
        if (base + 3 < N_NODES) v3 = cnt[base + 3];
    }
    int ts = v0 + v1 + v2 + v3;
    lds[tid] = ts;
    __syncthreads();
    for (int off = 1; off < 256; off <<= 1) {
        int x = (tid >= off) ? lds[tid - off] : 0;
        __syncthreads();
        lds[tid] += x;
        __syncthreads();
    }
    int excl = lds[tid] - ts;
    if (tid == 255) bsums[blockIdx.x] = lds[255];
    int run = excl;
    if (base     < N_NODES) offs[base]     = run; run += v0;
    if (base + 1 < N_NODES) offs[base + 1] = run; run += v1;
    if (base + 2 < N_NODES) offs[base + 2] = run; run += v2;
    if (base + 3 < N_NODES) offs[base + 3] = run;
}

__global__ __launch_bounds__(128) void scan2_kernel(int* __restrict__ bsums, int nb) {
    __shared__ int lds[128];
    int tid = threadIdx.x;
    int v = (tid < nb) ? bsums[tid] : 0;
    lds[tid] = v;
    __syncthreads();
    for (int off = 1; off < 128; off <<= 1) {
        int x = (tid >= off) ? lds[tid - off] : 0;
        __syncthreads();
        lds[tid] += x;
        __syncthreads();
    }
    if (tid < nb) bsums[tid] = lds[tid] - v;   // exclusive
}

__global__ __launch_bounds__(256) void scan3_kernel(int* __restrict__ offs,
                                                    const int* __restrict__ bsums,
                                                    int* __restrict__ cursor) {
    int i = blockIdx.x * 256 + threadIdx.x;
    if (i < N_NODES) {
        int o = offs[i] + bsums[i >> 10];
        offs[i] = o;
        cursor[i] = o;
    }
}

__global__ __launch_bounds__(256) void scatter_kernel(const int* __restrict__ dst,
                                                      int* __restrict__ cursor,
                                                      int* __restrict__ edge_list) {
    int e = blockIdx.x * 256 + threadIdx.x;
    if (e < N_EDGES) {
        int p = atomicAdd(&cursor[dst[e]], 1);
        edge_list[p] = e;
    }
}

// ---------------------------------------------------------------------------
// Aggregation: one wave per node, lane k owns feature k. No LDS, no barriers.
// ---------------------------------------------------------------------------
__global__ __launch_bounds__(256) void agg_kernel(
    const float* __restrict__ h,
    const float* __restrict__ dist,
    const int* __restrict__ src_idx,
    const int* __restrict__ offs,
    const int* __restrict__ cnt,
    const int* __restrict__ edge_list,
    float* __restrict__ out)
{
    int w    = threadIdx.x >> 6;
    int lane = threadIdx.x & 63;
    int node = blockIdx.x * 4 + w;
    if (node >= N_NODES) return;

    int beg = __builtin_amdgcn_readfirstlane(offs[node]);
    int m   = __builtin_amdgcn_readfirstlane(cnt[node]);
    float mu = (float)lane * (1.0f / 63.0f);
    float acc = 0.0f;

    int i = 0;
    for (; i + 1 < m; i += 2) {
        int e0 = __builtin_amdgcn_readfirstlane(edge_list[beg + i]);
        int e1 = __builtin_amdgcn_readfirstlane(edge_list[beg + i + 1]);
        float d0 = dist[e0], d1 = dist[e1];
        int s0 = src_idx[e0], s1 = src_idx[e1];
        float c0 = edge_coef(d0, mu);
        float c1 = edge_coef(d1, mu);
        acc = fmaf(h[(size_t)s0 * 64 + lane], c0, acc);
        acc = fmaf(h[(size_t)s1 * 64 + lane], c1, acc);
    }
    if (i < m) {
        int e0 = __builtin_amdgcn_readfirstlane(edge_list[beg + i]);
        float d0 = dist[e0];
        int s0 = src_idx[e0];
        acc = fmaf(h[(size_t)s0 * 64 + lane], edge_coef(d0, mu), acc);
    }
    out[(size_t)node * 64 + lane] = acc;
}

// ---------------------------------------------------------------------------
// MLP in place on d_out: out[n] = softplus(agg[n]@W1+b1)@W2+b2
// 4 nodes per wave share each W LDS read; no in-loop barriers (each wave
// only touches its own sRow/sHid rows -> wave-internal LDS ordering suffices).
// ---------------------------------------------------------------------------
__global__ __launch_bounds__(256) void mlp_kernel(
    float* __restrict__ io,
    const float* __restrict__ W1, const float* __restrict__ b1,
    const float* __restrict__ W2, const float* __restrict__ b2)
{
    __shared__ float sW1[64 * 64];
    __shared__ float sW2[64 * 64];
    __shared__ float sRow[16][64];
    __shared__ float sHid[16][64];

    int tid = threadIdx.x;
    for (int i = tid; i < 64 * 64; i += 256) {
        sW1[i] = W1[i];
        sW2[i] = W2[i];
    }
    __syncthreads();

    int lane = tid & 63;
    int w    = tid >> 6;
    float bb1 = b1[lane];
    float bb2 = b2[lane];

    // 16 nodes per block iteration; 6250 blocks * 16 == 100000 exactly.
    for (int base = blockIdx.x * 16; base < N_NODES; base += gridDim.x * 16) {
        int n0 = base + w * 4;   // this wave's 4 nodes
        int r  = w * 4;

        sRow[r + 0][lane] = io[(size_t)(n0 + 0) * 64 + lane];
        sRow[r + 1][lane] = io[(size_t)(n0 + 1) * 64 + lane];
        sRow[r + 2][lane] = io[(size_t)(n0 + 2) * 64 + lane];
        sRow[r + 3][lane] = io[(size_t)(n0 + 3) * 64 + lane];

        float a0 = bb1, a1 = bb1, a2 = bb1, a3 = bb1;
        #pragma unroll
        for (int k = 0; k < 64; ++k) {
            float wv = sW1[k * 64 + lane];
            a0 = fmaf(sRow[r + 0][k], wv, a0);
            a1 = fmaf(sRow[r + 1][k], wv, a1);
            a2 = fmaf(sRow[r + 2][k], wv, a2);
            a3 = fmaf(sRow[r + 3][k], wv, a3);
        }
        sHid[r + 0][lane] = (a0 > 20.0f) ? a0 : log1pf(__expf(a0));
        sHid[r + 1][lane] = (a1 > 20.0f) ? a1 : log1pf(__expf(a1));
        sHid[r + 2][lane] = (a2 > 20.0f) ? a2 : log1pf(__expf(a2));
        sHid[r + 3][lane] = (a3 > 20.0f) ? a3 : log1pf(__expf(a3));

        float c0 = bb2, c1 = bb2, c2 = bb2, c3 = bb2;
        #pragma unroll
        for (int k = 0; k < 64; ++k) {
            float wv = sW2[k * 64 + lane];
            c0 = fmaf(sHid[r + 0][k], wv, c0);
            c1 = fmaf(sHid[r + 1][k], wv, c1);
            c2 = fmaf(sHid[r + 2][k], wv, c2);
            c3 = fmaf(sHid[r + 3][k], wv, c3);
        }
        io[(size_t)(n0 + 0) * 64 + lane] = c0;
        io[(size_t)(n0 + 1) * 64 + lane] = c1;
        io[(size_t)(n0 + 2) * 64 + lane] = c2;
        io[(size_t)(n0 + 3) * 64 + lane] = c3;
    }
}

// ---------------------------------------------------------------------------
// Fallback (ws too small): atomic scatter-add path from round 2.
// ---------------------------------------------------------------------------
__global__ __launch_bounds__(256) void schnet_edge_kernel(
    const float* __restrict__ h,
    const float* __restrict__ dist,
    const int* __restrict__ src_idx,
    const int* __restrict__ dst_idx,
    float* __restrict__ agg)
{
    long long idx = (long long)blockIdx.x * 256 + threadIdx.x;
    int e = (int)(idx >> 6);
    if (e >= N_EDGES) return;
    int k = (int)(idx & 63);
    float d = dist[e];
    float c = edge_coef(d, (float)k * (1.0f / 63.0f));
    int s  = src_idx[e];
    int dn = dst_idx[e];
    atomicAdd(&agg[(long long)dn * 64 + k], h[(long long)s * 64 + k] * c);
}

extern "C" void kernel_launch(void* const* d_in, const int* in_sizes, int n_in,
                              void* d_out, int out_size, void* d_ws, size_t ws_size,
                              hipStream_t stream) {
    const float* h    = (const float*)d_in[0];
    const float* dist = (const float*)d_in[1];
    const float* W1   = (const float*)d_in[2];
    const float* b1   = (const float*)d_in[3];
    const float* W2   = (const float*)d_in[4];
    const float* b2   = (const float*)d_in[5];
    const int* src    = (const int*)d_in[6];
    const int* dst    = (const int*)d_in[7];
    float* out        = (float*)d_out;

    // ws layout (ints): cnt[N] | offs[N] | cursor[N] | bsums[128] | edge_list[E]
    size_t needed = ((size_t)3 * N_NODES + 128 + N_EDGES) * sizeof(int);

    if (ws_size >= needed) {
        int* cnt       = (int*)d_ws;
        int* offs      = cnt + N_NODES;
        int* cursor    = offs + N_NODES;
        int* bsums     = cursor + N_NODES;
        int* edge_list = bsums + 128;

        hipMemsetAsync(cnt, 0, (size_t)N_NODES * sizeof(int), stream);

        int eblocks = (N_EDGES + 255) / 256;
        count_kernel<<<eblocks, 256, 0, stream>>>(dst, cnt);
        scan1_kernel<<<NSCAN_BLOCKS, 256, 0, stream>>>(cnt, offs, bsums);
        scan2_kernel<<<1, 128, 0, stream>>>(bsums, NSCAN_BLOCKS);
        scan3_kernel<<<(N_NODES + 255) / 256, 256, 0, stream>>>(offs, bsums, cursor);
        scatter_kernel<<<eblocks, 256, 0, stream>>>(dst, cursor, edge_list);

        agg_kernel<<<(N_NODES + 3) / 4, 256, 0, stream>>>(h, dist, src, offs, cnt,
                                                          edge_list, out);
    } else {
        hipMemsetAsync(out, 0, (size_t)N_NODES * IN_FEATS * sizeof(float), stream);
        long long total = (long long)N_EDGES * 64;
        schnet_edge_kernel<<<(int)((total + 255) / 256), 256, 0, stream>>>(
            h, dist, src, dst, out);
    }

    mlp_kernel<<<N_NODES / 16, 256, 0, stream>>>(out, W1, b1, W2, b2);
}

// Round 4
// 352.083 us; speedup vs baseline: 1.3706x; 1.3706x over previous
//
#include <hip/hip_runtime.h>
#include <math.h>

#define IN_FEATS 64
#define N_NODES 100000
#define N_EDGES 1600000
#define NSCAN_BLOCKS ((N_NODES + 1023) / 1024)   // 98

// ---------------------------------------------------------------------------
// edge coefficient: rbf(d, mu_k) * smooth_cutoff(d)
// ---------------------------------------------------------------------------
__device__ __forceinline__ float edge_coef(float d, float mu) {
    float t = d - mu;
    float rbf = __expf(-64.0f * t * t);          // gamma = 64/(1-0)
    float x  = (d - 0.8f) * 5.0f;                // /(1.0-0.8)
    float xc = fminf(fmaxf(x, 0.0f), 1.0f);
    float ramp = 0.5f * (__cosf(3.14159265358979323846f * xc) + 1.0f);
    float fc = (d <= 0.8f) ? 1.0f : ((d >= 1.0f) ? 0.0f : ramp);
    return rbf * fc;
}

// ---------------------------------------------------------------------------
// CSR build: count -> scan -> scatter(packed src+dist)
// ---------------------------------------------------------------------------
__global__ __launch_bounds__(256) void count_kernel(const int* __restrict__ dst,
                                                    int* __restrict__ cnt) {
    int e = blockIdx.x * 256 + threadIdx.x;
    if (e < N_EDGES) atomicAdd(&cnt[dst[e]], 1);
}

__global__ __launch_bounds__(256) void scan1_kernel(const int* __restrict__ cnt,
                                                    int* __restrict__ offs,
                                                    int* __restrict__ bsums) {
    __shared__ int lds[256];
    int tid = threadIdx.x;
    int base = blockIdx.x * 1024 + tid * 4;
    int v0 = 0, v1 = 0, v2 = 0, v3 = 0;
    if (base + 3 < N_NODES) {
        const int4 v = *reinterpret_cast<const int4*>(&cnt[base]);
        v0 = v.x; v1 = v.y; v2 = v.z; v3 = v.w;
    } else {
        if (base     < N_NODES) v0 = cnt[base];
        if (base + 1 < N_NODES) v1 = cnt[base + 1];
        if (base + 2 < N_NODES) v2 = cnt[base + 2];
        if (base + 3 < N_NODES) v3 = cnt[base + 3];
    }
    int ts = v0 + v1 + v2 + v3;
    lds[tid] = ts;
    __syncthreads();
    for (int off = 1; off < 256; off <<= 1) {
        int x = (tid >= off) ? lds[tid - off] : 0;
        __syncthreads();
        lds[tid] += x;
        __syncthreads();
    }
    int excl = lds[tid] - ts;
    if (tid == 255) bsums[blockIdx.x] = lds[255];
    int run = excl;
    if (base     < N_NODES) offs[base]     = run; run += v0;
    if (base + 1 < N_NODES) offs[base + 1] = run; run += v1;
    if (base + 2 < N_NODES) offs[base + 2] = run; run += v2;
    if (base + 3 < N_NODES) offs[base + 3] = run;
}

__global__ __launch_bounds__(128) void scan2_kernel(int* __restrict__ bsums, int nb) {
    __shared__ int lds[128];
    int tid = threadIdx.x;
    int v = (tid < nb) ? bsums[tid] : 0;
    lds[tid] = v;
    __syncthreads();
    for (int off = 1; off < 128; off <<= 1) {
        int x = (tid >= off) ? lds[tid - off] : 0;
        __syncthreads();
        lds[tid] += x;
        __syncthreads();
    }
    if (tid < nb) bsums[tid] = lds[tid] - v;   // exclusive
}

__global__ __launch_bounds__(256) void scan3_kernel(int* __restrict__ offs,
                                                    const int* __restrict__ bsums,
                                                    int* __restrict__ cursor) {
    int i = blockIdx.x * 256 + threadIdx.x;
    if (i < N_NODES) {
        int o = offs[i] + bsums[i >> 10];
        offs[i] = o;
        cursor[i] = o;
    }
    if (i == 0) offs[N_NODES] = N_EDGES;   // sentinel
}

// packed per-edge record, bucketed by dst: {src_idx, dist}
__global__ __launch_bounds__(256) void scatter_kernel(const int* __restrict__ dst,
                                                      const int* __restrict__ src,
                                                      const float* __restrict__ dist,
                                                      int* __restrict__ cursor,
                                                      int2* __restrict__ edge_data) {
    int e = blockIdx.x * 256 + threadIdx.x;
    if (e < N_EDGES) {
        int p = atomicAdd(&cursor[dst[e]], 1);
        int2 rec;
        rec.x = src[e];
        rec.y = __float_as_int(dist[e]);
        edge_data[p] = rec;
    }
}

// ---------------------------------------------------------------------------
// Aggregation: one wave per node, lane k owns feature k.
// 2-deep chain (edge_data -> h gather), unrolled x4 for ILP.
// ---------------------------------------------------------------------------
__global__ __launch_bounds__(256) void agg_kernel(
    const float* __restrict__ h,
    const int* __restrict__ offs,
    const int2* __restrict__ edge_data,
    float* __restrict__ out)
{
    int w    = threadIdx.x >> 6;
    int lane = threadIdx.x & 63;
    int node = blockIdx.x * 4 + w;
    if (node >= N_NODES) return;

    int beg = offs[node];
    int end = offs[node + 1];
    int m   = end - beg;
    float mu = (float)lane * (1.0f / 63.0f);
    float acc = 0.0f;

    const int2* ed = edge_data + beg;
    int i = 0;
    for (; i + 3 < m; i += 4) {
        int2 r0 = ed[i + 0];
        int2 r1 = ed[i + 1];
        int2 r2 = ed[i + 2];
        int2 r3 = ed[i + 3];
        const float* p0 = h + (size_t)r0.x * 64 + lane;
        const float* p1 = h + (size_t)r1.x * 64 + lane;
        const float* p2 = h + (size_t)r2.x * 64 + lane;
        const float* p3 = h + (size_t)r3.x * 64 + lane;
        float h0 = *p0, h1 = *p1, h2 = *p2, h3 = *p3;
        float c0 = edge_coef(__int_as_float(r0.y), mu);
        float c1 = edge_coef(__int_as_float(r1.y), mu);
        float c2 = edge_coef(__int_as_float(r2.y), mu);
        float c3 = edge_coef(__int_as_float(r3.y), mu);
        acc = fmaf(h0, c0, acc);
        acc = fmaf(h1, c1, acc);
        acc = fmaf(h2, c2, acc);
        acc = fmaf(h3, c3, acc);
    }
    for (; i < m; ++i) {
        int2 r0 = ed[i];
        float hv = h[(size_t)r0.x * 64 + lane];
        acc = fmaf(hv, edge_coef(__int_as_float(r0.y), mu), acc);
    }
    out[(size_t)node * 64 + lane] = acc;
}

// ---------------------------------------------------------------------------
// MLP in place on d_out: out[n] = softplus(agg[n]@W1+b1)@W2+b2
// Grid-stride with few blocks so W staging is amortized; 4 nodes/wave.
// ---------------------------------------------------------------------------
__global__ __launch_bounds__(256) void mlp_kernel(
    float* __restrict__ io,
    const float* __restrict__ W1, const float* __restrict__ b1,
    const float* __restrict__ W2, const float* __restrict__ b2)
{
    __shared__ float sW1[64 * 64];
    __shared__ float sW2[64 * 64];
    __shared__ float sRow[16][64];
    __shared__ float sHid[16][64];

    int tid = threadIdx.x;
    // 4096 floats each, float4-staged: 4 iterations of 256 threads
    for (int i = tid; i < 1024; i += 256) {
        reinterpret_cast<float4*>(sW1)[i] = reinterpret_cast<const float4*>(W1)[i];
        reinterpret_cast<float4*>(sW2)[i] = reinterpret_cast<const float4*>(W2)[i];
    }
    __syncthreads();

    int lane = tid & 63;
    int w    = tid >> 6;
    float bb1 = b1[lane];
    float bb2 = b2[lane];

    // 16 nodes per block-iteration; N_NODES % 16 == 0.
    for (int base = blockIdx.x * 16; base < N_NODES; base += gridDim.x * 16) {
        int n0 = base + w * 4;   // this wave's 4 nodes
        int r  = w * 4;

        sRow[r + 0][lane] = io[(size_t)(n0 + 0) * 64 + lane];
        sRow[r + 1][lane] = io[(size_t)(n0 + 1) * 64 + lane];
        sRow[r + 2][lane] = io[(size_t)(n0 + 2) * 64 + lane];
        sRow[r + 3][lane] = io[(size_t)(n0 + 3) * 64 + lane];

        float a0 = bb1, a1 = bb1, a2 = bb1, a3 = bb1;
        #pragma unroll
        for (int k = 0; k < 64; ++k) {
            float wv = sW1[k * 64 + lane];
            a0 = fmaf(sRow[r + 0][k], wv, a0);
            a1 = fmaf(sRow[r + 1][k], wv, a1);
            a2 = fmaf(sRow[r + 2][k], wv, a2);
            a3 = fmaf(sRow[r + 3][k], wv, a3);
        }
        sHid[r + 0][lane] = (a0 > 20.0f) ? a0 : log1pf(__expf(a0));
        sHid[r + 1][lane] = (a1 > 20.0f) ? a1 : log1pf(__expf(a1));
        sHid[r + 2][lane] = (a2 > 20.0f) ? a2 : log1pf(__expf(a2));
        sHid[r + 3][lane] = (a3 > 20.0f) ? a3 : log1pf(__expf(a3));

        float c0 = bb2, c1 = bb2, c2 = bb2, c3 = bb2;
        #pragma unroll
        for (int k = 0; k < 64; ++k) {
            float wv = sW2[k * 64 + lane];
            c0 = fmaf(sHid[r + 0][k], wv, c0);
            c1 = fmaf(sHid[r + 1][k], wv, c1);
            c2 = fmaf(sHid[r + 2][k], wv, c2);
            c3 = fmaf(sHid[r + 3][k], wv, c3);
        }
        io[(size_t)(n0 + 0) * 64 + lane] = c0;
        io[(size_t)(n0 + 1) * 64 + lane] = c1;
        io[(size_t)(n0 + 2) * 64 + lane] = c2;
        io[(size_t)(n0 + 3) * 64 + lane] = c3;
    }
}

// ---------------------------------------------------------------------------
// Fallback (ws too small): atomic scatter-add path.
// ---------------------------------------------------------------------------
__global__ __launch_bounds__(256) void schnet_edge_kernel(
    const float* __restrict__ h,
    const float* __restrict__ dist,
    const int* __restrict__ src_idx,
    const int* __restrict__ dst_idx,
    float* __restrict__ agg)
{
    long long idx = (long long)blockIdx.x * 256 + threadIdx.x;
    int e = (int)(idx >> 6);
    if (e >= N_EDGES) return;
    int k = (int)(idx & 63);
    float d = dist[e];
    float c = edge_coef(d, (float)k * (1.0f / 63.0f));
    int s  = src_idx[e];
    int dn = dst_idx[e];
    atomicAdd(&agg[(long long)dn * 64 + k], h[(long long)s * 64 + k] * c);
}

extern "C" void kernel_launch(void* const* d_in, const int* in_sizes, int n_in,
                              void* d_out, int out_size, void* d_ws, size_t ws_size,
                              hipStream_t stream) {
    const float* h    = (const float*)d_in[0];
    const float* dist = (const float*)d_in[1];
    const float* W1   = (const float*)d_in[2];
    const float* b1   = (const float*)d_in[3];
    const float* W2   = (const float*)d_in[4];
    const float* b2   = (const float*)d_in[5];
    const int* src    = (const int*)d_in[6];
    const int* dst    = (const int*)d_in[7];
    float* out        = (float*)d_out;

    // ws layout (ints): cnt[N] | offs[N+1] | cursor[N] | bsums[128] | edge_data[2*E]
    size_t needed = ((size_t)3 * N_NODES + 1 + 128 + 2 * (size_t)N_EDGES) * sizeof(int);

    if (ws_size >= needed) {
        int* cnt        = (int*)d_ws;
        int* offs       = cnt + N_NODES;            // N+1 entries
        int* cursor     = offs + N_NODES + 1;
        int* bsums      = cursor + N_NODES;
        int2* edge_data = (int2*)(bsums + 128);

        hipMemsetAsync(cnt, 0, (size_t)N_NODES * sizeof(int), stream);

        int eblocks = (N_EDGES + 255) / 256;
        count_kernel<<<eblocks, 256, 0, stream>>>(dst, cnt);
        scan1_kernel<<<NSCAN_BLOCKS, 256, 0, stream>>>(cnt, offs, bsums);
        scan2_kernel<<<1, 128, 0, stream>>>(bsums, NSCAN_BLOCKS);
        scan3_kernel<<<(N_NODES + 255) / 256, 256, 0, stream>>>(offs, bsums, cursor);
        scatter_kernel<<<eblocks, 256, 0, stream>>>(dst, src, dist, cursor, edge_data);

        agg_kernel<<<(N_NODES + 3) / 4, 256, 0, stream>>>(h, offs, edge_data, out);
    } else {
        hipMemsetAsync(out, 0, (size_t)N_NODES * IN_FEATS * sizeof(float), stream);
        long long total = (long long)N_EDGES * 64;
        schnet_edge_kernel<<<(int)((total + 255) / 256), 256, 0, stream>>>(
            h, dist, src, dst, out);
    }

    mlp_kernel<<<1024, 256, 0, stream>>>(out, W1, b1, W2, b2);
}